// Round 4
// baseline (826.946 us; speedup 1.0000x reference)
//
#include <hip/hip_runtime.h>

typedef unsigned short u16;
typedef __bf16 bf16x8 __attribute__((ext_vector_type(8)));
typedef float f32x4 __attribute__((ext_vector_type(4)));
typedef unsigned uint4v __attribute__((ext_vector_type(4)));

#define MFMA(a, b, c) __builtin_amdgcn_mfma_f32_16x16x32_bf16(a, b, c, 0, 0, 0)

static __device__ __forceinline__ u16 f2bf(float f) {
  unsigned u = __float_as_uint(f);
  u = u + 0x7FFFu + ((u >> 16) & 1u);   // round-to-nearest-even
  return (u16)(u >> 16);
}

static __device__ __forceinline__ unsigned pk2(float lo, float hi) {
  unsigned r;
  asm("v_cvt_pk_bf16_f32 %0, %1, %2" : "=v"(r) : "v"(lo), "v"(hi));
  return r;
}

static __device__ __forceinline__ f32x4 fzero() {
  f32x4 z; z[0] = 0.f; z[1] = 0.f; z[2] = 0.f; z[3] = 0.f; return z;
}

// ---- kernel 0: convert qkv_w (196608) + proj_w (65536) fp32 -> bf16 into ws ----
__global__ void cvt_w(const float* __restrict__ qw, const float* __restrict__ pw,
                      u16* __restrict__ o) {
  int i = blockIdx.x * 256 + threadIdx.x;      // grid covers 262144 exactly
  float v = (i < 196608) ? qw[i] : pw[i - 196608];
  o[i] = f2bf(v);
}

static __device__ __forceinline__ void load_x(const float* __restrict__ x, int w,
                                              int tid, float4 xr[4]) {
  const int bb = w >> 10, wh = (w >> 5) & 31, ww = w & 31;
  const float* xb = x + ((size_t)bb << 24);
  #pragma unroll
  for (int i = 0; i < 4; ++i) {
    int flat = i * 1024 + tid;
    int t = flat >> 6, c4 = flat & 63;
    int row = wh * 8 + (t >> 3), col = ww * 8 + (t & 7);
    xr[i] = *(const float4*)(xb + ((size_t)(row * 256 + col) << 8) + c4 * 4);
  }
}

// LDS layout (u16 units), dynamic 152576 B:
//   Xs [64][264] @0 (16896 u16) -- aliased as Os for the proj input
//   per head h @ 16896 + h*7424: Qs [64][40]; Ks [64][40]; Vt [32][72]
#define SMEM_U16 76288

// Persistent kernel: 256 blocks (1/CU) x 1024 threads (16 waves, 4/SIMD).
// Each block loops over 16 windows. Weights are STREAMED from L2 (register-
// resident weights would blow the 128-VGPR cap that 4 waves/SIMD imposes);
// only bias (32 VGPR) + proj bias are persistent.
// Attention: wave = (head h=wv>>1, tok_q half=wv&1); S^T = K·Q^T so softmax
// rows are lane-local; P stays in registers (cvt_pk + quad shuffles feed PV).
__global__ __launch_bounds__(1024, 4) void swin(
    const float* __restrict__ x, const u16* __restrict__ wqkv,
    const u16* __restrict__ wproj, const float* __restrict__ pb,
    const float* __restrict__ bias, float* __restrict__ out) {

  extern __shared__ u16 smem[];

  const int tid  = threadIdx.x;
  const int wv   = tid >> 6;            // 0..15
  const int lane = tid & 63;
  const int l15  = lane & 15;
  const int quad = lane >> 4;
  const int h    = wv >> 1;             // head for attention phase
  const int hf   = wv & 1;              // tok_q half (32 rows)

  u16* Xs = smem;
  u16* Qh = smem + 16896 + h * 7424;    // this wave's attention-head buffers
  u16* Kh = Qh + 2560;
  u16* Vh = Qh + 5120;

  // ---- persistent register state (loaded once, reused for 16 windows) ----
  float bv[4][2][4];                    // bias[h][tok_q = hf*32+n*16+l15][tok_k = mk*16+quad*4+e]
  {
    const float* bh = bias + h * 4096 + (hf * 32 + l15) * 64 + quad * 4;
    #pragma unroll
    for (int n = 0; n < 2; ++n)
      #pragma unroll
      for (int mk = 0; mk < 4; ++mk)
        #pragma unroll
        for (int e = 0; e < 4; ++e)
          bv[mk][n][e] = bh[n * 1024 + mk * 16 + e];
  }
  const float pbv = pb[wv * 16 + l15];
  const float scale = 0.17677669529663687f;   // 1/sqrt(32)

  // streamed-weight base pointers (wave-constant)
  const u16* wq0 = wqkv + (size_t)(wv * 48 + l15) * 256 + quad * 8;
  const u16* wp0 = wproj + (size_t)(wv * 16 + l15) * 256 + quad * 8;

  const int wbase = blockIdx.x << 4;
  float4 xr[4];
  load_x(x, wbase, tid, xr);            // prefetch window 0

  for (int wi = 0; wi < 16; ++wi) {
    const int w  = wbase + wi;
    const int bb = w >> 10, wh = (w >> 5) & 31, ww = w & 31;

    __syncthreads();                    // b0: prev proj's Os reads done
    // ---- stage x window (from prefetch regs) -> bf16 LDS ----
    #pragma unroll
    for (int i = 0; i < 4; ++i) {
      int flat = i * 1024 + tid;
      int t = flat >> 6, c4 = flat & 63;
      unsigned p0 = (unsigned)f2bf(xr[i].x) | ((unsigned)f2bf(xr[i].y) << 16);
      unsigned p1 = (unsigned)f2bf(xr[i].z) | ((unsigned)f2bf(xr[i].w) << 16);
      *(uint2*)&Xs[t * 264 + c4 * 4] = make_uint2(p0, p1);
    }
    __syncthreads();                    // b1: Xs ready

    // ---- QKV GEMM: 3 owned N-tiles (rows wv*48..+47), B streamed from L2 ----
    {
      f32x4 acc[3][4];
      #pragma unroll
      for (int t = 0; t < 3; ++t)
        #pragma unroll
        for (int m = 0; m < 4; ++m) acc[t][m] = fzero();

      #pragma unroll
      for (int kk = 0; kk < 8; ++kk) {
        bf16x8 af[4];
        #pragma unroll
        for (int m = 0; m < 4; ++m)
          af[m] = *(const bf16x8*)&Xs[(m * 16 + l15) * 264 + kk * 32 + quad * 8];
        #pragma unroll
        for (int t = 0; t < 3; ++t) {
          bf16x8 bf = *(const bf16x8*)(wq0 + (size_t)t * 4096 + kk * 32);
          #pragma unroll
          for (int m = 0; m < 4; ++m) acc[t][m] = MFMA(af[m], bf, acc[t][m]);
        }
      }
      // epilogue: route each 16-row tile to its head's Q/K/V buffer
      #pragma unroll
      for (int t = 0; t < 3; ++t) {
        int grow = wv * 48 + t * 16;
        int ty = grow >> 8, hd = (grow >> 5) & 7, sub = (grow >> 4) & 1;
        u16* hb = smem + 16896 + hd * 7424;
        int dl = sub * 16 + l15;
        if (ty == 2) {                  // V: transposed [d][tok]
          u16* vt = hb + 5120;
          #pragma unroll
          for (int m = 0; m < 4; ++m) {
            unsigned p0 = pk2(acc[t][m][0], acc[t][m][1]);
            unsigned p1 = pk2(acc[t][m][2], acc[t][m][3]);
            *(uint2*)&vt[dl * 72 + m * 16 + quad * 4] = make_uint2(p0, p1);
          }
        } else {                        // Q/K: tok-major [64][40]
          u16* dst = hb + (ty ? 2560 : 0);
          #pragma unroll
          for (int m = 0; m < 4; ++m)
            #pragma unroll
            for (int e = 0; e < 4; ++e)
              dst[(m * 16 + quad * 4 + e) * 40 + dl] = f2bf(acc[t][m][e]);
        }
      }
    }
    __syncthreads();                    // b2: Q/K/V ready; Xs reads done (Os overlay safe)

    if (wi < 15) load_x(x, w + 1, tid, xr);   // prefetch next window under attn+proj

    // ---- S^T = K·Q^T (*scale + bias); lane-local softmax; P packed in regs ----
    unsigned pks[4][2][2];              // [mk][n][r]: bf16 pair (e=2r, e=2r+1)
    {
      f32x4 sa[4][2];
      #pragma unroll
      for (int mk = 0; mk < 4; ++mk)
        #pragma unroll
        for (int n = 0; n < 2; ++n) sa[mk][n] = fzero();

      bf16x8 ka[4], qb[2];
      #pragma unroll
      for (int mk = 0; mk < 4; ++mk)
        ka[mk] = *(const bf16x8*)&Kh[(mk * 16 + l15) * 40 + quad * 8];
      #pragma unroll
      for (int n = 0; n < 2; ++n)
        qb[n] = *(const bf16x8*)&Qh[(hf * 32 + n * 16 + l15) * 40 + quad * 8];
      #pragma unroll
      for (int mk = 0; mk < 4; ++mk)
        #pragma unroll
        for (int n = 0; n < 2; ++n) sa[mk][n] = MFMA(ka[mk], qb[n], sa[mk][n]);

      // lane holds S^T[tok_k = mk*16+quad*4+e][tok_q = hf*32+n*16+l15]
      float p[4][2][4];
      #pragma unroll
      for (int mk = 0; mk < 4; ++mk)
        #pragma unroll
        for (int n = 0; n < 2; ++n)
          #pragma unroll
          for (int e = 0; e < 4; ++e)
            p[mk][n][e] = sa[mk][n][e] * scale + bv[mk][n][e];

      #pragma unroll
      for (int n = 0; n < 2; ++n) {
        float mx = p[0][n][0];
        #pragma unroll
        for (int mk = 0; mk < 4; ++mk)
          #pragma unroll
          for (int e = 0; e < 4; ++e) mx = fmaxf(mx, p[mk][n][e]);
        mx = fmaxf(mx, __shfl_xor(mx, 16, 64));
        mx = fmaxf(mx, __shfl_xor(mx, 32, 64));
        float sum = 0.f;
        #pragma unroll
        for (int mk = 0; mk < 4; ++mk)
          #pragma unroll
          for (int e = 0; e < 4; ++e) {
            float pe = __expf(p[mk][n][e] - mx);
            p[mk][n][e] = pe; sum += pe;
          }
        sum += __shfl_xor(sum, 16, 64);
        sum += __shfl_xor(sum, 32, 64);
        float ri = __builtin_amdgcn_rcpf(sum);
        #pragma unroll
        for (int mk = 0; mk < 4; ++mk) {
          pks[mk][n][0] = pk2(p[mk][n][0] * ri, p[mk][n][1] * ri);
          pks[mk][n][1] = pk2(p[mk][n][2] * ri, p[mk][n][3] * ri);
        }
      }
    }

    // ---- O = P·V; P A-frags built by quad shuffles; write Os (= Xs alias) ----
    {
      const int srcA = l15 + ((quad & 1) << 5);   // lane holding the needed k-offsets
      const bool hiMk = (quad & 2) != 0;
      f32x4 oacc[2][2];
      #pragma unroll
      for (int n = 0; n < 2; ++n)
        #pragma unroll
        for (int dt = 0; dt < 2; ++dt) oacc[n][dt] = fzero();

      #pragma unroll
      for (int kp = 0; kp < 2; ++kp) {
        bf16x8 vvb[2];
        #pragma unroll
        for (int dt = 0; dt < 2; ++dt)
          vvb[dt] = *(const bf16x8*)&Vh[(dt * 16 + l15) * 72 + kp * 32 + quad * 8];
        #pragma unroll
        for (int n = 0; n < 2; ++n) {
          unsigned a0 = __shfl(pks[2 * kp][n][0], srcA, 64);
          unsigned a1 = __shfl(pks[2 * kp][n][1], srcA, 64);
          unsigned a2 = __shfl(pks[2 * kp][n][0], srcA + 16, 64);
          unsigned a3 = __shfl(pks[2 * kp][n][1], srcA + 16, 64);
          unsigned b0 = __shfl(pks[2 * kp + 1][n][0], srcA, 64);
          unsigned b1 = __shfl(pks[2 * kp + 1][n][1], srcA, 64);
          unsigned b2 = __shfl(pks[2 * kp + 1][n][0], srcA + 16, 64);
          unsigned b3 = __shfl(pks[2 * kp + 1][n][1], srcA + 16, 64);
          uint4v u;
          u[0] = hiMk ? b0 : a0;
          u[1] = hiMk ? b1 : a1;
          u[2] = hiMk ? b2 : a2;
          u[3] = hiMk ? b3 : a3;
          bf16x8 pa = __builtin_bit_cast(bf16x8, u);
          #pragma unroll
          for (int dt = 0; dt < 2; ++dt) oacc[n][dt] = MFMA(pa, vvb[dt], oacc[n][dt]);
        }
      }
      #pragma unroll
      for (int n = 0; n < 2; ++n)
        #pragma unroll
        for (int dt = 0; dt < 2; ++dt)
          #pragma unroll
          for (int e = 0; e < 4; ++e)
            Xs[(hf * 32 + n * 16 + quad * 4 + e) * 264 + h * 32 + dt * 16 + l15] =
                f2bf(oacc[n][dt][e]);
    }
    __syncthreads();                    // b3: Os complete

    // ---- proj GEMM (B streamed) + bias, fp32 scatter store ----
    {
      f32x4 pacc[4];
      #pragma unroll
      for (int m = 0; m < 4; ++m) pacc[m] = fzero();
      #pragma unroll
      for (int kk = 0; kk < 8; ++kk) {
        bf16x8 af[4];
        #pragma unroll
        for (int m = 0; m < 4; ++m)
          af[m] = *(const bf16x8*)&Xs[(m * 16 + l15) * 264 + kk * 32 + quad * 8];
        bf16x8 bf = *(const bf16x8*)(wp0 + kk * 32);
        #pragma unroll
        for (int m = 0; m < 4; ++m) pacc[m] = MFMA(af[m], bf, pacc[m]);
      }
      float* ob = out + ((size_t)bb << 24);
      #pragma unroll
      for (int m = 0; m < 4; ++m)
        #pragma unroll
        for (int e = 0; e < 4; ++e) {
          int t = m * 16 + quad * 4 + e;
          int row = wh * 8 + (t >> 3), col = ww * 8 + (t & 7);
          ob[((size_t)(row * 256 + col) << 8) + wv * 16 + l15] = pacc[m][e] + pbv;
        }
    }
  }
}

extern "C" void kernel_launch(void* const* d_in, const int* in_sizes, int n_in,
                              void* d_out, int out_size, void* d_ws, size_t ws_size,
                              hipStream_t stream) {
  const float* x  = (const float*)d_in[0];
  const float* qw = (const float*)d_in[1];
  const float* pw = (const float*)d_in[2];
  const float* pb = (const float*)d_in[3];
  const float* bs = (const float*)d_in[4];
  u16* wbf = (u16*)d_ws;                 // 262144 bf16 = 512 KB of ws

  static bool lds_opt_in = false;
  if (!lds_opt_in) {                     // host-side, capture-safe, once per process
    hipFuncSetAttribute((const void*)swin,
                        hipFuncAttributeMaxDynamicSharedMemorySize, SMEM_U16 * 2);
    lds_opt_in = true;
  }

  cvt_w<<<1024, 256, 0, stream>>>(qw, pw, wbf);
  swin<<<256, 1024, SMEM_U16 * 2, stream>>>(x, wbf, wbf + 196608, pb, bs, (float*)d_out);
}